// Round 3
// baseline (275.599 us; speedup 1.0000x reference)
//
#include <hip/hip_runtime.h>

#define C_IN  128
#define C_RES 64
#define D     512
#define DD    (D * D)          // 262144 floats per c-slice
#define NC4   (DD / 4)         // 65536 float4 chunks per (o,i) plane

// ---------------------------------------------------------------------------
// K1: 3072 blocks x 256 = 786432 threads. Twelve partial-sum planes, each a
// 16-channel column sum: planes 0..7 cover W1 c[16p,16p+16), planes 8..11
// cover W2. Every thread: exactly 16 coalesced, independent float4 loads.
// Resident set hits the 32 waves/CU cap (8/SIMD) for max latency hiding.
// Also zeroes diff1|diff2 (98304 floats, contiguous).
// ---------------------------------------------------------------------------
__global__ __launch_bounds__(256)
void sum_zero_kernel(const float* __restrict__ W1,
                     const float* __restrict__ W2,
                     float* __restrict__ Sp,        // 12*DD floats
                     float* __restrict__ diff_zero) {
    int t = blockIdx.x * 256 + threadIdx.x;        // 0 .. 786431
    int plane = t >> 16;                           // 0..11
    int chunk = t & 0xFFFF;                        // 0..65535
    const float4* p = (plane < 8)
        ? (const float4*)W1 + (size_t)plane * 16 * NC4 + chunk
        : (const float4*)W2 + (size_t)(plane - 8) * 16 * NC4 + chunk;
    float4 acc = make_float4(0.f, 0.f, 0.f, 0.f);
#pragma unroll
    for (int c = 0; c < 16; ++c) {
        float4 w = p[(size_t)c * NC4];
        acc.x += w.x; acc.y += w.y; acc.z += w.z; acc.w += w.w;
    }
    ((float4*)Sp)[t] = acc;
    if (t < (C_IN + C_RES) * D) diff_zero[t] = 0.f;   // diff1 + diff2
}

// ---------------------------------------------------------------------------
// K2: 256 blocks x 512 threads (8 waves/CU, 2x round 2). Blocks 0..127:
// stage-1 argmax over sum of 8 W1-planes + scatter
//   diff1[c,n_i] += W1[c,n_i,i]*relu(x[c,i]).
// Blocks 128..255: stage-2 argmax over sum of 4 W2-planes -> node2,
// pre-gather w2v[c,i] = W2[c,n_i,i].
// 4 cols/block keeps 16B-contiguous lane quads in the argmax read.
// Tie-break = first (smallest o), matching jnp.argmax.
// ---------------------------------------------------------------------------
__global__ __launch_bounds__(512)
void argmax_scatter_kernel(const float* __restrict__ Sp,
                           const float* __restrict__ W1,
                           const float* __restrict__ W2,
                           const float* __restrict__ x,
                           float* __restrict__ diff1,
                           float* __restrict__ w2v,
                           int* __restrict__ node2) {
    __shared__ float lv[512];
    __shared__ int   li[512];
    __shared__ int   node_s[4];

    const int  tid = threadIdx.x;
    const bool st1 = blockIdx.x < 128;
    const int  i0  = (blockIdx.x & 127) * 4;
    const int  il  = tid & 3;
    const int  ol  = tid >> 2;                    // 0..127
    const float* __restrict__ S1p = Sp;
    const float* __restrict__ S2p = Sp + (size_t)8 * DD;

    float best = -__builtin_inff();
    int   bidx = D;                               // > any valid o
#pragma unroll
    for (int k = 0; k < 4; ++k) {
        int o   = ol + (k << 7);                  // ascending per thread
        int off = o * D + i0 + il;
        float v;
        if (st1) {
            v = 0.f;
#pragma unroll
            for (int pl = 0; pl < 8; ++pl) v += S1p[pl * DD + off];
        } else {
            v = S2p[off] + S2p[DD + off] + S2p[2 * DD + off] + S2p[3 * DD + off];
        }
        if (v > best) { best = v; bidx = o; }     // strict >: first wins
    }
    lv[tid] = best; li[tid] = bidx;
    __syncthreads();
    for (int s = 256; s >= 4; s >>= 1) {
        if (tid < s) {
            float v2 = lv[tid + s]; int i2 = li[tid + s];
            if (v2 > lv[tid] || (v2 == lv[tid] && i2 < li[tid])) {
                lv[tid] = v2; li[tid] = i2;
            }
        }
        __syncthreads();
    }
    if (tid < 4) {
        node_s[tid] = li[tid];
        if (!st1) node2[i0 + tid] = li[tid];
    }
    __syncthreads();

    if (st1) {
        // 128 c x 4 i = 512 ops, exactly 1 per thread
        int ii = tid & 3;
        int c  = tid >> 2;
        int i  = i0 + ii;
        int n  = node_s[ii];
        float xv = fmaxf(x[c * D + i], 0.f);
        float w  = W1[(size_t)c * DD + (size_t)n * D + i];
        atomicAdd(&diff1[c * D + n], w * xv);
    } else if (tid < C_RES * 4) {
        // 64 c x 4 i = 256 ops
        int ii = tid & 3;
        int c  = tid >> 2;
        int i  = i0 + ii;
        int n  = node_s[ii];
        w2v[c * D + i] = W2[(size_t)c * DD + (size_t)n * D + i];
    }
}

// ---------------------------------------------------------------------------
// K3: x2 = relu(bc1[c] + sum_cc Wc1[c,cc]*diff1[cc,i]);
//     diff2[c, node2[i]] += w2v[c,i] * x2
// 128 blocks x 256; c = blockIdx>>1, i = (blockIdx&1)*256+tid.
// ---------------------------------------------------------------------------
__global__ void conv1_scatter2_kernel(const float* __restrict__ Wc1,
                                      const float* __restrict__ bc1,
                                      const float* __restrict__ diff1,
                                      const float* __restrict__ w2v,
                                      const int* __restrict__ node2,
                                      float* __restrict__ diff2) {
    __shared__ float wc[C_IN];
    const int c = blockIdx.x >> 1;                // 0..63
    const int i = ((blockIdx.x & 1) << 8) + threadIdx.x;
    if (threadIdx.x < C_IN) wc[threadIdx.x] = Wc1[c * C_IN + threadIdx.x];
    __syncthreads();

    float acc = bc1[c];
#pragma unroll 8
    for (int cc = 0; cc < C_IN; ++cc)
        acc += wc[cc] * diff1[cc * D + i];        // lanes = consecutive i
    float x2 = fmaxf(acc, 0.f);
    int n = node2[i];
    atomicAdd(&diff2[c * D + n], w2v[c * D + i] * x2);
}

// ---------------------------------------------------------------------------
// K4: out[o,d] = relu(x[o,d]) + bc2[o] + sum_c Wc2[o,c]*diff2[c,d]
// 256 blocks x 256; o = blockIdx>>1, d = (blockIdx&1)*256+tid.
// ---------------------------------------------------------------------------
__global__ void final_kernel(const float* __restrict__ Wc2,
                             const float* __restrict__ bc2,
                             const float* __restrict__ diff2,
                             const float* __restrict__ x,
                             float* __restrict__ out) {
    __shared__ float wc[C_RES];
    const int o = blockIdx.x >> 1;                // 0..127
    const int d = ((blockIdx.x & 1) << 8) + threadIdx.x;
    if (threadIdx.x < C_RES) wc[threadIdx.x] = Wc2[o * C_RES + threadIdx.x];
    __syncthreads();

    float acc = bc2[o];
#pragma unroll 8
    for (int c = 0; c < C_RES; ++c)
        acc += wc[c] * diff2[c * D + d];
    out[o * D + d] = acc + fmaxf(x[o * D + d], 0.f);
}

extern "C" void kernel_launch(void* const* d_in, const int* in_sizes, int n_in,
                              void* d_out, int out_size, void* d_ws, size_t ws_size,
                              hipStream_t stream) {
    const float* x   = (const float*)d_in[0];   // (1, 128, 512)
    const float* W1  = (const float*)d_in[1];   // (128, 512, 512)
    const float* Wc1 = (const float*)d_in[2];   // (64, 128)
    const float* bc1 = (const float*)d_in[3];   // (64,)
    const float* W2  = (const float*)d_in[4];   // (64, 512, 512)
    const float* Wc2 = (const float*)d_in[5];   // (128, 64)
    const float* bc2 = (const float*)d_in[6];   // (128,)
    float* out = (float*)d_out;                 // (1, 128, 512) fp32

    // Workspace carve-up (floats); diff1|diff2 contiguous for K1's zeroing.
    float* ws    = (float*)d_ws;
    float* Sp    = ws;                          // 12 * 262144 partial planes
    float* diff1 = Sp + (size_t)12 * DD;        // 65536
    float* diff2 = diff1 + C_IN * D;            // 32768 (contiguous after diff1)
    float* w2v   = diff2 + C_RES * D;           // 32768
    int*   node2 = (int*)(w2v + C_RES * D);     // 512

    // K1: stream W1+W2 (201 MB) into 12 partial planes + zero diff1/diff2
    sum_zero_kernel<<<3072, 256, 0, stream>>>(W1, W2, Sp, diff1);
    // K2: argmax both stages (summing partials) + stage-1 scatter + W2 gather
    argmax_scatter_kernel<<<256, 512, 0, stream>>>(Sp, W1, W2, x,
                                                   diff1, w2v, node2);
    // K3: stage-1 1x1 conv (+bias,relu) fused with stage-2 scatter
    conv1_scatter2_kernel<<<128, 256, 0, stream>>>(Wc1, bc1, diff1, w2v,
                                                   node2, diff2);
    // K4: stage-2 1x1 conv + bias + residual relu(x)
    final_kernel<<<256, 256, 0, stream>>>(Wc2, bc2, diff2, x, out);
}